// Round 5
// baseline (352.849 us; speedup 1.0000x reference)
//
#include <hip/hip_runtime.h>
#include <hip/hip_bf16.h>
#include <stdint.h>

typedef _Float16 f16;
typedef _Float16 f16x4 __attribute__((ext_vector_type(4)));
typedef _Float16 f16x8 __attribute__((ext_vector_type(8)));
typedef float f32x4 __attribute__((ext_vector_type(4)));

// async global->LDS copy, 16B per lane. LDS dest must be wave-uniform-base + lane*16.
#define ASYNC_COPY16(gsrc, ldst)                                                   \
    __builtin_amdgcn_global_load_lds(                                              \
        (__attribute__((address_space(1))) void*)(gsrc),                           \
        (__attribute__((address_space(3))) void*)(ldst), 16, 0, 0)

#define MFMA16(a, b, c) __builtin_amdgcn_mfma_f32_16x16x32_f16((a), (b), (c), 0, 0, 0)

// ---------------------------------------------------------------------------
// fp32 -> f16 conversion, 4 elems/thread (float4 load, 8B store)
// ---------------------------------------------------------------------------
__global__ __launch_bounds__(256) void cvt_f32_to_f16(const float* __restrict__ in,
                                                      f16* __restrict__ out, int n4) {
    int i = blockIdx.x * 256 + threadIdx.x;
    if (i >= n4) return;
    float4 v = ((const float4*)in)[i];
    f16x4 o;
    o.x = (f16)v.x; o.y = (f16)v.y; o.z = (f16)v.z; o.w = (f16)v.w;
    ((f16x4*)out)[i] = o;
}

// three conversions in one launch: y -> yb, W1 -> w1b, W2 -> w2b
__global__ __launch_bounds__(256) void cvt3_f32_to_f16(const float* __restrict__ y,
                                                       const float* __restrict__ W1,
                                                       const float* __restrict__ W2,
                                                       f16* __restrict__ yb,
                                                       f16* __restrict__ w1b,
                                                       f16* __restrict__ w2b,
                                                       int nY4, int nW4) {
    int i = blockIdx.x * 256 + threadIdx.x;
    const float* src;
    f16* dst;
    int off;
    if (i < nY4) {
        src = y; dst = yb; off = i;
    } else if (i < nY4 + nW4) {
        src = W1; dst = w1b; off = i - nY4;
    } else {
        src = W2; dst = w2b; off = i - nY4 - nW4;
        if (off >= nW4) return;
    }
    float4 v = ((const float4*)src)[off];
    f16x4 o;
    o.x = (f16)v.x; o.y = (f16)v.y; o.z = (f16)v.z; o.w = (f16)v.w;
    ((f16x4*)dst)[off] = o;
}

// ---------------------------------------------------------------------------
// C = A(MxK) * B(NxK)^T + bias, f16 in, fp32 accumulate.
// Tile 128x256, BK=64, 512 thr = 8 waves (2M x 4N), per-wave 64x64.
// grid (N/256)x(M/128) = 256 blocks = 1/CU.
//
// Intra-wave 4-phase software pipeline, ONE barrier per tile.
//   Phase = (m-half, k-half): 8 MFMA. B-frags read once per k-half, reused
//   by both m-halves. ds_reads of phase p+1 are issued BEFORE the MFMA
//   cluster of phase p (sched_barrier(0)-pinned); the compiler derives the
//   counted lgkmcnt(N) waits from the dep graph. Each tile's LAST MFMA
//   cluster is deferred past the tile barrier so it overlaps the next
//   tile's first read drain.
//
// Hazard audit (explicit fences only; counts exact and wave-uniform):
//   - RAW stage->ds_read: per-wave vmcnt(6) fence BEFORE the single tile
//     barrier (6 loads of tile t+2 in flight); crossing the barrier proves
//     every wave's tile-(t+1) staging landed. Last tiles fence vmcnt(0).
//   - WAR ds_read->stage: tile t's stages overwrite buf[(t-1)%3]. All reads
//     of that buffer were issued in iteration t-1 AND completed before the
//     t-1 tile barrier: the boundary fence includes lgkmcnt(0), so even the
//     deferred-frag ds_reads (aP0/aP1/bP, whose first MFMA consumer is
//     after the barrier) are register-resident before any wave crosses.
//     (Without lgkmcnt(0) the compiler may sink their wait past the
//     barrier -> in-flight ds_read vs staging DMA race, the round-0 class.)
//   - Deferred-p3 MFMA reads pre-barrier-loaded registers only.
//
// LDS rows are 128 B; XOR swizzle (seg ^= row&7) applied on the GLOBAL source
// (global_load_lds forces linear LDS writes) and undone at ds_read
// (measured: SQ_LDS_BANK_CONFLICT = 0 with this scheme).
// STORE_F16: 1 -> f16 output (h), 0 -> fp32 output.
// ---------------------------------------------------------------------------
template <int STORE_F16>
__global__ __launch_bounds__(512, 1) void gemm_bt(const f16* __restrict__ A,
                                                  const f16* __restrict__ Bm,
                                                  const float* __restrict__ bias,
                                                  void* __restrict__ Cout,
                                                  int M, int N, int K) {
    constexpr int BM = 128, BN = 256, BK = 64;
    __shared__ __align__(16) f16 sA[3][BM * BK];  // 3 x 16 KB
    __shared__ __align__(16) f16 sB[3][BN * BK];  // 3 x 32 KB

    const int tid   = threadIdx.x;
    const int lane  = tid & 63;
    const int wave  = tid >> 6;   // 0..7
    const int waveM = wave >> 2;  // 0..1
    const int waveN = wave & 3;   // 0..3

    const int bm = blockIdx.y * BM;
    const int bn = blockIdx.x * BN;

    const f16* Aptr = A + (size_t)bm * K;
    const f16* Bptr = Bm + (size_t)bn * K;

    // staging geometry: one "sweep" = 512 thr x 16B = 8 KB = 64 rows of 128B.
    // A tile = 2 sweeps, B tile = 4 sweeps. Thread t writes LDS bytes
    // [s*8192 + t*16, +16) (linear per wave as global_load_lds requires);
    // global segment is XOR-swizzled: seg = (t&7) ^ (row&7).
    const int srow = tid >> 3;  // 0..63
    const int sseg = tid & 7;

    const f16* gA[2];
    const f16* gB[4];
#pragma unroll
    for (int s = 0; s < 2; s++) {
        const int row = s * 64 + srow;
        const int seg = sseg ^ (row & 7);
        gA[s] = Aptr + (size_t)row * K + seg * 8;
    }
#pragma unroll
    for (int s = 0; s < 4; s++) {
        const int row = s * 64 + srow;
        const int seg = sseg ^ (row & 7);
        gB[s] = Bptr + (size_t)row * K + seg * 8;
    }
    const int ldst = tid * 8;  // f16 elements (= tid*16 bytes)

#define STAGE_A(s, buf, k0) ASYNC_COPY16(gA[s] + (k0), &sA[buf][(s)*4096 + ldst])
#define STAGE_B(s, buf, k0) ASYNC_COPY16(gB[s] + (k0), &sB[buf][(s)*4096 + ldst])

    f32x4 acc[4][4] = {};

    const int quad = lane >> 4;
    const int l16  = lane & 15;

    const int iters = K / BK;  // 64

    int cbuf = 0;

    // fragment loaders (cbuf captured by reference)
    auto rdA = [&](int mi, int kh) -> f16x8 {
        const int row = waveM * 64 + mi * 16 + l16;
        const int seg = (kh * 4 + quad) ^ (l16 & 7);
        return *(const f16x8*)&sA[cbuf][row * BK + seg * 8];
    };
    auto rdB = [&](int ni, int kh) -> f16x8 {
        const int row = waveN * 64 + ni * 16 + l16;
        const int seg = (kh * 4 + quad) ^ (l16 & 7);
        return *(const f16x8*)&sB[cbuf][row * BK + seg * 8];
    };

    // ---- prologue: stage tile 0 -> buf0, tile 1 -> buf1 (12 loads)
#pragma unroll
    for (int s = 0; s < 2; s++) STAGE_A(s, 0, 0);
#pragma unroll
    for (int s = 0; s < 4; s++) STAGE_B(s, 0, 0);
#pragma unroll
    for (int s = 0; s < 2; s++) STAGE_A(s, 1, BK);
#pragma unroll
    for (int s = 0; s < 4; s++) STAGE_B(s, 1, BK);
    asm volatile("s_waitcnt vmcnt(6)" ::: "memory");  // tile 0 landed (own loads)
    __builtin_amdgcn_s_barrier();                     // ...published by every wave

    f16x8 aP0 = {}, aP1 = {}, bP[4] = {};  // deferred-phase frags (carry across barrier)

    for (int t = 0; t < iters; ++t) {
        const int pbuf = (cbuf >= 1) ? cbuf - 1 : 2;  // buffer of tile t+2
        const bool st  = (t + 2 < iters);
        const int k0   = (t + 2) * BK;

        // ---- issue R(p0): kh0 A m-half0 (2) + kh0 B (4); first 3 stages
        f16x8 a0[2], b0[4];
#pragma unroll
        for (int mi = 0; mi < 2; mi++) a0[mi] = rdA(mi, 0);
#pragma unroll
        for (int ni = 0; ni < 4; ni++) b0[ni] = rdB(ni, 0);
        if (st) {
            STAGE_A(0, pbuf, k0);
            STAGE_A(1, pbuf, k0);
            STAGE_B(0, pbuf, k0);
        }
        __builtin_amdgcn_sched_barrier(0);

        // ---- deferred p3 of tile t-1: overlaps R(p0)'s LDS drain
        if (t > 0) {
            __builtin_amdgcn_s_setprio(1);
#pragma unroll
            for (int ni = 0; ni < 4; ni++) {
                acc[2][ni] = MFMA16(aP0, bP[ni], acc[2][ni]);
                acc[3][ni] = MFMA16(aP1, bP[ni], acc[3][ni]);
            }
            __builtin_amdgcn_s_setprio(0);
        }
        __builtin_amdgcn_sched_barrier(0);

        // ---- issue R(p1): kh0 A m-half1 (2)
        f16x8 a1[2];
#pragma unroll
        for (int mi = 0; mi < 2; mi++) a1[mi] = rdA(2 + mi, 0);
        __builtin_amdgcn_sched_barrier(0);

        // ---- p0 MFMA (acc rows 0..1, kh0)
        __builtin_amdgcn_s_setprio(1);
#pragma unroll
        for (int ni = 0; ni < 4; ni++) {
            acc[0][ni] = MFMA16(a0[0], b0[ni], acc[0][ni]);
            acc[1][ni] = MFMA16(a0[1], b0[ni], acc[1][ni]);
        }
        __builtin_amdgcn_s_setprio(0);
        __builtin_amdgcn_sched_barrier(0);

        // ---- issue R(p2): kh1 A m-half0 (2) + kh1 B (4)
        f16x8 a2[2];
#pragma unroll
        for (int mi = 0; mi < 2; mi++) a2[mi] = rdA(mi, 1);
#pragma unroll
        for (int ni = 0; ni < 4; ni++) bP[ni] = rdB(ni, 1);
        __builtin_amdgcn_sched_barrier(0);

        // ---- p1 MFMA (acc rows 2..3, kh0)
        __builtin_amdgcn_s_setprio(1);
#pragma unroll
        for (int ni = 0; ni < 4; ni++) {
            acc[2][ni] = MFMA16(a1[0], b0[ni], acc[2][ni]);
            acc[3][ni] = MFMA16(a1[1], b0[ni], acc[3][ni]);
        }
        __builtin_amdgcn_s_setprio(0);
        __builtin_amdgcn_sched_barrier(0);

        // ---- issue R(p3): kh1 A m-half1 (2); last 3 stages
        aP0 = rdA(2, 1);
        aP1 = rdA(3, 1);
        if (st) {
            STAGE_B(1, pbuf, k0);
            STAGE_B(2, pbuf, k0);
            STAGE_B(3, pbuf, k0);
        }
        __builtin_amdgcn_sched_barrier(0);

        // ---- p2 MFMA (acc rows 0..1, kh1)
        __builtin_amdgcn_s_setprio(1);
#pragma unroll
        for (int ni = 0; ni < 4; ni++) {
            acc[0][ni] = MFMA16(a2[0], bP[ni], acc[0][ni]);
            acc[1][ni] = MFMA16(a2[1], bP[ni], acc[1][ni]);
        }
        __builtin_amdgcn_s_setprio(0);

        // ---- tile-boundary fence BEFORE the single barrier.
        // vmcnt: tile-(t+1) staging landed (6 of t+2 still in flight).
        // lgkmcnt(0): deferred frags (aP0/aP1/bP) are register-resident, so
        // next iteration's staging can safely overwrite buf[(t-1)%3].
        if (st) {
            asm volatile("s_waitcnt vmcnt(6) lgkmcnt(0)" ::: "memory");
        } else {
            asm volatile("s_waitcnt vmcnt(0) lgkmcnt(0)" ::: "memory");
        }
        __builtin_amdgcn_s_barrier();

        cbuf = (cbuf >= 2) ? 0 : cbuf + 1;
    }

    // ---- final deferred p3 (tile iters-1)
#pragma unroll
    for (int ni = 0; ni < 4; ni++) {
        acc[2][ni] = MFMA16(aP0, bP[ni], acc[2][ni]);
        acc[3][ni] = MFMA16(aP1, bP[ni], acc[3][ni]);
    }

#undef STAGE_A
#undef STAGE_B

    // epilogue: C/D layout col = lane&15, row = quad*4 + reg
#pragma unroll
    for (int ni = 0; ni < 4; ni++) {
        const int col = bn + waveN * 64 + ni * 16 + l16;
        const float bv = bias[col];
#pragma unroll
        for (int mi = 0; mi < 4; mi++) {
            const int row0 = bm + waveM * 64 + mi * 16 + quad * 4;
#pragma unroll
            for (int r = 0; r < 4; r++) {
                float v = acc[mi][ni][r] + bv;
                if (STORE_F16)
                    ((f16*)Cout)[(size_t)(row0 + r) * N + col] = (f16)v;
                else
                    ((float*)Cout)[(size_t)(row0 + r) * N + col] = v;
            }
        }
    }
}

// ---------------------------------------------------------------------------
// replicator: per row r, dot = sum_k y*out; out = y*(out - dot). In-place.
// one block (256 thr) per row, float4 loads; second pass mostly L2-hits.
// ---------------------------------------------------------------------------
__global__ __launch_bounds__(256) void replicator(const float* __restrict__ y,
                                                  float* __restrict__ out, int N) {
    const int row = blockIdx.x;
    const float4* y4 = (const float4*)(y + (size_t)row * N);
    float4* o4 = (float4*)(out + (size_t)row * N);
    const int n4 = N / 4;

    float p = 0.f;
    for (int i = threadIdx.x; i < n4; i += 256) {
        float4 a = y4[i], b = o4[i];
        p += a.x * b.x + a.y * b.y + a.z * b.z + a.w * b.w;
    }
#pragma unroll
    for (int off = 32; off > 0; off >>= 1) p += __shfl_down(p, off, 64);

    __shared__ float sred[4];
    if ((threadIdx.x & 63) == 0) sred[threadIdx.x >> 6] = p;
    __syncthreads();
    const float dot = sred[0] + sred[1] + sred[2] + sred[3];

    for (int i = threadIdx.x; i < n4; i += 256) {
        float4 a = y4[i], b = o4[i];
        float4 r;
        r.x = a.x * (b.x - dot);
        r.y = a.y * (b.y - dot);
        r.z = a.z * (b.z - dot);
        r.w = a.w * (b.w - dot);
        o4[i] = r;
    }
}

extern "C" void kernel_launch(void* const* d_in, const int* in_sizes, int n_in,
                              void* d_out, int out_size, void* d_ws, size_t ws_size,
                              hipStream_t stream) {
    // inputs: 0=t(1), 1=y(B*N), 2=W1(N*N), 3=b1(N), 4=W2(N*N), 5=b2(N)
    const float* y  = (const float*)d_in[1];
    const float* W1 = (const float*)d_in[2];
    const float* b1 = (const float*)d_in[3];
    const float* W2 = (const float*)d_in[4];
    const float* b2 = (const float*)d_in[5];

    const int N = in_sizes[3];            // 4096
    const int B = in_sizes[1] / N;        // 2048
    float* out = (float*)d_out;

    const size_t szY = (size_t)B * N;     // elements
    const size_t szW = (size_t)N * N;

    const int yn4 = (int)(szY / 4);
    const int wn4 = (int)(szW / 4);

    dim3 g1(N / 256, B / 128);            // 16 x 16 = 256 blocks, 8 waves each

    const size_t need_big = (szY + 2 * szW + szY) * sizeof(f16);  // yb|w1b|w2b|hb

    if (ws_size >= need_big) {
        f16* yb  = (f16*)d_ws;
        f16* w1b = yb + szY;
        f16* w2b = w1b + szW;
        f16* hb  = w2b + szW;

        const int tot4 = yn4 + 2 * wn4;
        cvt3_f32_to_f16<<<(tot4 + 255) / 256, 256, 0, stream>>>(y, W1, W2, yb, w1b, w2b,
                                                                yn4, wn4);
        gemm_bt<1><<<g1, 512, 0, stream>>>(yb, w1b, b1, hb, B, N, N);
        gemm_bt<0><<<g1, 512, 0, stream>>>(hb, w2b, b2, out, B, N, N);
    } else {
        // fallback: reuse one weight buffer (yb | wb | hb)
        f16* yb = (f16*)d_ws;
        f16* wb = yb + szY;
        f16* hb = wb + szW;

        cvt_f32_to_f16<<<yn4 / 256, 256, 0, stream>>>(y, yb, yn4);
        cvt_f32_to_f16<<<wn4 / 256, 256, 0, stream>>>(W1, wb, wn4);
        gemm_bt<1><<<g1, 512, 0, stream>>>(yb, wb, b1, hb, B, N, N);
        cvt_f32_to_f16<<<wn4 / 256, 256, 0, stream>>>(W2, wb, wn4);
        gemm_bt<0><<<g1, 512, 0, stream>>>(hb, wb, b2, out, B, N, N);
    }

    replicator<<<B, 256, 0, stream>>>(y, out, N);
}